// Round 1
// baseline (777.442 us; speedup 1.0000x reference)
//
#include <hip/hip_runtime.h>

// TreeDecoderTeacherForced — round 0 baseline (fp32 vector, LDS-tiled GEMM).
//
// Structure: quadconv is a gathered GEMM  A[N,576] @ W[576,64]  where A's row n
// is the concat of 9 gathered 64-float neighbor rows (-1 -> zeros). We tile
// 64 nodes x 64 out-channels per block, staging per-neighbor-chunk a
// transposed A tile colT[k][n] and W tile wT[k][c] in LDS, then a 4x4
// register-tiled FMA loop. Heads (value = h@Wv, split = h@Ws) reuse the LDS
// buffers with the relu'd h. Child pass gathers h[parent]*gate on the fly.

constexpr int NPARENT = 200000;
constexpr int NCHILD  = 300000;
constexpr int CD      = 64;     // C_IN == HID == 64
constexpr int COLP    = 68;     // padded LDS row stride (floats); 68%4==0 keeps
                                // 16B alignment for float4 reads, 68%32!=0
                                // breaks the worst bank-conflict patterns.

template<bool IS_CHILD>
__global__ __launch_bounds__(256)
void quad_kernel(const float* __restrict__ src_feat,   // parent: feat; child: h (ws)
                 const int*   __restrict__ neigh,      // [N][9], -1 = missing
                 const int*   __restrict__ parent_idx, // child only
                 const float* __restrict__ split_gt,   // child only
                 const float* __restrict__ W,          // [576][64] row-major
                 const float* __restrict__ bvec,       // [64]
                 const float* __restrict__ Ws,         // [64]
                 const float* __restrict__ Wv,         // [64][64]
                 float* __restrict__ split_out,        // [N]
                 float* __restrict__ value_out,        // [N][64]
                 float* __restrict__ h_out,            // parent: ws h; child: unused
                 int N)
{
    __shared__ float colT[64 * COLP];   // [k][node]
    __shared__ float wT[64 * COLP];     // [k][chan]

    const int tid  = threadIdx.x;
    const int cq   = tid & 15;    // channel quad (staging + GEMM tc)
    const int rr   = tid >> 4;    // 0..15 (staging row group + GEMM tn)
    const int base = blockIdx.x * 64;

    // accumulator init = bias (per out-channel, same for every node)
    const float4 bv = *reinterpret_cast<const float4*>(bvec + cq * 4);
    float acc[4][4];
#pragma unroll
    for (int i = 0; i < 4; ++i) {
        acc[i][0] = bv.x; acc[i][1] = bv.y; acc[i][2] = bv.z; acc[i][3] = bv.w;
    }

    // ---- conv GEMM over 9 neighbor chunks (k = j*64 + in_channel) ----
    for (int j = 0; j < 9; ++j) {
        __syncthreads();   // previous chunk's reads done before restage
        // stage gathered A chunk, transposed: colT[in_chan][node]
#pragma unroll
        for (int s = 0; s < 4; ++s) {
            const int n    = rr + s * 16;
            const int node = base + n;
            float4 v = make_float4(0.f, 0.f, 0.f, 0.f);
            if (node < N) {
                const int g = neigh[node * 9 + j];
                if (g >= 0) {
                    if (IS_CHILD) {
                        const int   p    = parent_idx[g];
                        const float gate = split_gt[p];
                        v = *reinterpret_cast<const float4*>(src_feat + (size_t)p * CD + cq * 4);
                        v.x *= gate; v.y *= gate; v.z *= gate; v.w *= gate;
                    } else {
                        v = *reinterpret_cast<const float4*>(src_feat + (size_t)g * CD + cq * 4);
                    }
                }
            }
            colT[(cq * 4 + 0) * COLP + n] = v.x;
            colT[(cq * 4 + 1) * COLP + n] = v.y;
            colT[(cq * 4 + 2) * COLP + n] = v.z;
            colT[(cq * 4 + 3) * COLP + n] = v.w;
        }
        // stage W chunk: wT[k][c] = W[j*64+k][c]
#pragma unroll
        for (int s = 0; s < 4; ++s) {
            const int k = rr + s * 16;
            *reinterpret_cast<float4*>(wT + k * COLP + cq * 4) =
                *reinterpret_cast<const float4*>(W + (size_t)(j * 64 + k) * CD + cq * 4);
        }
        __syncthreads();

#pragma unroll 16
        for (int k = 0; k < 64; ++k) {
            const float4 a4 = *reinterpret_cast<const float4*>(colT + k * COLP + rr * 4);
            const float4 w4 = *reinterpret_cast<const float4*>(wT   + k * COLP + cq * 4);
            const float av[4] = {a4.x, a4.y, a4.z, a4.w};
            const float wv[4] = {w4.x, w4.y, w4.z, w4.w};
#pragma unroll
            for (int i = 0; i < 4; ++i)
#pragma unroll
                for (int l = 0; l < 4; ++l)
                    acc[i][l] += av[i] * wv[l];
        }
    }

    // ---- ReLU ----
#pragma unroll
    for (int i = 0; i < 4; ++i)
#pragma unroll
        for (int l = 0; l < 4; ++l)
            acc[i][l] = fmaxf(acc[i][l], 0.f);

    __syncthreads();   // conv reads of colT/wT done before overwrite

    // write h: global ws (parent pass) + transposed hT into colT for heads
#pragma unroll
    for (int i = 0; i < 4; ++i) {
        const int n    = rr * 4 + i;
        const int node = base + n;
        if (!IS_CHILD) {
            if (node < N) {
                const float4 hv = make_float4(acc[i][0], acc[i][1], acc[i][2], acc[i][3]);
                *reinterpret_cast<float4*>(h_out + (size_t)node * CD + cq * 4) = hv;
            }
        }
        colT[(cq * 4 + 0) * COLP + n] = acc[i][0];
        colT[(cq * 4 + 1) * COLP + n] = acc[i][1];
        colT[(cq * 4 + 2) * COLP + n] = acc[i][2];
        colT[(cq * 4 + 3) * COLP + n] = acc[i][3];
    }
    // stage Wv
#pragma unroll
    for (int s = 0; s < 4; ++s) {
        const int k = rr + s * 16;
        *reinterpret_cast<float4*>(wT + k * COLP + cq * 4) =
            *reinterpret_cast<const float4*>(Wv + (size_t)k * CD + cq * 4);
    }
    __syncthreads();

    // ---- value head GEMM: value[n][c] = sum_k h[n][k] * Wv[k][c] ----
    float vacc[4][4];
#pragma unroll
    for (int i = 0; i < 4; ++i)
#pragma unroll
        for (int l = 0; l < 4; ++l)
            vacc[i][l] = 0.f;

#pragma unroll 16
    for (int k = 0; k < 64; ++k) {
        const float4 a4 = *reinterpret_cast<const float4*>(colT + k * COLP + rr * 4);
        const float4 w4 = *reinterpret_cast<const float4*>(wT   + k * COLP + cq * 4);
        const float av[4] = {a4.x, a4.y, a4.z, a4.w};
        const float wv[4] = {w4.x, w4.y, w4.z, w4.w};
#pragma unroll
        for (int i = 0; i < 4; ++i)
#pragma unroll
            for (int l = 0; l < 4; ++l)
                vacc[i][l] += av[i] * wv[l];
    }
#pragma unroll
    for (int i = 0; i < 4; ++i) {
        const int node = base + rr * 4 + i;
        if (node < N) {
            const float4 vv = make_float4(vacc[i][0], vacc[i][1], vacc[i][2], vacc[i][3]);
            *reinterpret_cast<float4*>(value_out + (size_t)node * CD + cq * 4) = vv;
        }
    }

    // ---- split head: split[n] = dot(h[n], Ws); 4 lanes per node ----
    const int sn = tid >> 2;
    const int qq = tid & 3;
    float sp = 0.f;
#pragma unroll
    for (int u = 0; u < 16; ++u) {
        const int k2 = qq * 16 + u;
        sp += colT[k2 * COLP + sn] * Ws[k2];
    }
    sp += __shfl_xor(sp, 1);
    sp += __shfl_xor(sp, 2);
    if (qq == 0) {
        const int node = base + sn;
        if (node < N) split_out[node] = sp;
    }
}

extern "C" void kernel_launch(void* const* d_in, const int* in_sizes, int n_in,
                              void* d_out, int out_size, void* d_ws, size_t ws_size,
                              hipStream_t stream) {
    const float* feat       = (const float*)d_in[0];
    const int*   neigh_d    = (const int*)d_in[1];
    const int*   neigh_d1   = (const int*)d_in[2];
    const int*   parent_idx = (const int*)d_in[3];
    const float* split_gt   = (const float*)d_in[4];
    const float* W1  = (const float*)d_in[5];
    const float* b1  = (const float*)d_in[6];
    const float* W2  = (const float*)d_in[7];
    const float* b2  = (const float*)d_in[8];
    const float* Ws1 = (const float*)d_in[9];
    const float* Wv1 = (const float*)d_in[10];
    const float* Ws2 = (const float*)d_in[11];
    const float* Wv2 = (const float*)d_in[12];

    float* out    = (float*)d_out;
    float* split1 = out;
    float* value1 = out + NPARENT;
    float* split2 = out + NPARENT + (size_t)NPARENT * CD;
    float* value2 = split2 + NCHILD;

    float* h_ws = (float*)d_ws;   // [NPARENT][64] relu'd parent hidden state

    quad_kernel<false><<<NPARENT / 64, 256, 0, stream>>>(
        feat, neigh_d, nullptr, nullptr, W1, b1, Ws1, Wv1,
        split1, value1, h_ws, NPARENT);

    quad_kernel<true><<<(NCHILD + 63) / 64, 256, 0, stream>>>(
        h_ws, neigh_d1, parent_idx, split_gt, W2, b2, Ws2, Wv2,
        split2, value2, nullptr, NCHILD);
}

// Round 3
// 187.820 us; speedup vs baseline: 4.1393x; 4.1393x over previous
//
#include <hip/hip_runtime.h>

// TreeDecoderTeacherForced — R2: bf16 MFMA (16x16x32), LDS XOR-swizzle,
// 2-phase staged pipeline, bf16 h workspace (halves child gather traffic).
// (R1 resubmit: renamed ushort4 alias -> us4; HIP owns the name ushort4.)

using short8 = __attribute__((ext_vector_type(8))) short;
using us4    = __attribute__((ext_vector_type(4))) unsigned short;
using f32x4  = __attribute__((ext_vector_type(4))) float;
typedef unsigned int u32;
typedef unsigned short u16;

constexpr int NPARENT = 200000;
constexpr int NCHILD  = 300000;

__device__ __forceinline__ u16 f2bf(float x) {        // fp32 -> bf16 RNE
    u32 u = __builtin_bit_cast(u32, x);
    u32 r = (u + 0x7fffu + ((u >> 16) & 1u)) >> 16;
    return (u16)r;
}
__device__ __forceinline__ float bf2f(u16 x) {
    u32 u = ((u32)x) << 16;
    return __builtin_bit_cast(float, u);
}
// swizzled byte offset in a [64 rows][64 bf16] tile (row stride 128 B).
// XOR of bits 4-6 spreads the 16B frag slots across banks (2-way = free).
__device__ __forceinline__ int swz(int row, int byteInRow) {
    return row * 128 + (byteInRow ^ ((row & 7) << 4));
}

// ---------------- prep: transpose weights to bf16 Wt[c][k] ----------------
__global__ __launch_bounds__(256)
void prep_w(const float* __restrict__ W1, const float* __restrict__ W2,
            const float* __restrict__ Wv1, const float* __restrict__ Wv2,
            u16* __restrict__ Wt1, u16* __restrict__ Wt2,
            u16* __restrict__ Wv1t, u16* __restrict__ Wv2t)
{
    int t = blockIdx.x * 256 + threadIdx.x;
    if (t < 576 * 64) {
        int k = t >> 6, c = t & 63;          // W[k][c] row-major
        Wt1[c * 576 + k] = f2bf(W1[t]);
        Wt2[c * 576 + k] = f2bf(W2[t]);
    }
    if (t < 64 * 64) {
        int k = t >> 6, c = t & 63;
        Wv1t[c * 64 + k] = f2bf(Wv1[t]);
        Wv2t[c * 64 + k] = f2bf(Wv2[t]);
    }
}

// ---------------- main fused conv + heads kernel ----------------
template<bool IS_CHILD>
__global__ __launch_bounds__(256)
void quad_mfma(const float*  __restrict__ feat,       // parent src
               const u16*    __restrict__ h_src,      // child src (bf16 h)
               const int*    __restrict__ neigh,      // [N][9], -1 missing
               const int*    __restrict__ parent_idx, // child only
               const float*  __restrict__ split_gt,   // child only, in {0,1}
               const u16*    __restrict__ Wt,         // [64][576] bf16
               const float*  __restrict__ bvec,       // [64]
               const float*  __restrict__ Ws,         // [64]
               const u16*    __restrict__ Wvt,        // [64][64] bf16
               float* __restrict__ split_out,
               float* __restrict__ value_out,
               u16*   __restrict__ h_out,             // parent only (bf16)
               int N)
{
    __shared__ u16 aL[2][64 * 64];
    __shared__ u16 wL[2][64 * 64];

    const int tid  = threadIdx.x;
    const int lane = tid & 63;
    const int w    = tid >> 6;        // wave id: nodes [w*16, w*16+16)
    const int cq   = lane & 15;
    const int kh   = lane >> 4;       // 0..3
    const int base = blockIdx.x * 64;
    const int ln   = tid >> 2;        // staging: local node / weight row 0..63
    const int s    = tid & 3;         // staging: 16-col sub-slot

    // ---- staging registers (issue-early / write-late, T14 pattern) ----
    float4 avP[4];
    short8 avC[2];
    short8 wv2[2];

    auto issueA = [&](int j) {
        if (IS_CHILD) { avC[0] = short8{0,0,0,0,0,0,0,0}; avC[1] = avC[0]; }
        else {
            #pragma unroll
            for (int u = 0; u < 4; ++u) avP[u] = make_float4(0.f,0.f,0.f,0.f);
        }
        const int node = base + ln;
        if (node < N) {
            const int g = neigh[node * 9 + j];
            if (g >= 0) {
                if (IS_CHILD) {
                    const int p = parent_idx[g];
                    if (split_gt[p] != 0.0f) {            // gate is exactly 0/1
                        const u16* src = h_src + (size_t)p * 64 + s * 16;
                        avC[0] = *reinterpret_cast<const short8*>(src);
                        avC[1] = *reinterpret_cast<const short8*>(src + 8);
                    }
                } else {
                    const float* src = feat + (size_t)g * 64 + s * 16;
                    #pragma unroll
                    for (int u = 0; u < 4; ++u)
                        avP[u] = *reinterpret_cast<const float4*>(src + u * 4);
                }
            }
        }
    };
    auto writeA = [&](int buf) {
        char* aB = (char*)aL[buf];
        if (IS_CHILD) {
            #pragma unroll
            for (int u = 0; u < 2; ++u)
                *reinterpret_cast<short8*>(aB + swz(ln, s * 32 + u * 16)) = avC[u];
        } else {
            #pragma unroll
            for (int u = 0; u < 4; ++u) {
                us4 t4 = { f2bf(avP[u].x), f2bf(avP[u].y),
                           f2bf(avP[u].z), f2bf(avP[u].w) };
                *reinterpret_cast<us4*>(aB + swz(ln, s * 32 + u * 8)) = t4;
            }
        }
    };
    auto issueW = [&](int j) {
        const u16* src = Wt + (size_t)ln * 576 + j * 64 + s * 16;
        wv2[0] = *reinterpret_cast<const short8*>(src);
        wv2[1] = *reinterpret_cast<const short8*>(src + 8);
    };
    auto writeW = [&](int buf) {
        char* wB = (char*)wL[buf];
        #pragma unroll
        for (int u = 0; u < 2; ++u)
            *reinterpret_cast<short8*>(wB + swz(ln, s * 32 + u * 16)) = wv2[u];
    };
    auto stageWv = [&](int buf) {
        const u16* src = Wvt + (size_t)ln * 64 + s * 16;
        short8 a = *reinterpret_cast<const short8*>(src);
        short8 b = *reinterpret_cast<const short8*>(src + 8);
        char* wB = (char*)wL[buf];
        *reinterpret_cast<short8*>(wB + swz(ln, s * 32))      = a;
        *reinterpret_cast<short8*>(wB + swz(ln, s * 32 + 16)) = b;
    };

    // ---- accumulators: init with bias broadcast along rows ----
    f32x4 acc[4];
    #pragma unroll
    for (int cf = 0; cf < 4; ++cf) {
        float b = bvec[cf * 16 + cq];
        acc[cf] = f32x4{b, b, b, b};
    }

    auto computeChunk = [&](int buf, f32x4* ac) {
        const char* aB = (const char*)aL[buf];
        const char* wB = (const char*)wL[buf];
        #pragma unroll
        for (int ks = 0; ks < 2; ++ks) {
            const int arow = w * 16 + cq;
            short8 afrag = *reinterpret_cast<const short8*>(aB + swz(arow, ks * 64 + kh * 16));
            #pragma unroll
            for (int cf = 0; cf < 4; ++cf) {
                const int brow = cf * 16 + cq;
                short8 bfrag = *reinterpret_cast<const short8*>(wB + swz(brow, ks * 64 + kh * 16));
                ac[cf] = __builtin_amdgcn_mfma_f32_16x16x32_bf16(afrag, bfrag, ac[cf], 0, 0, 0);
            }
        }
    };

    // ---- prologue: stage chunk 0 ----
    issueA(0); issueW(0);
    writeA(0); writeW(0);
    __syncthreads();

    // ---- 9-chunk pipelined conv GEMM ----
    for (int j = 0; j < 9; ++j) {
        const int cur = j & 1;
        if (j < 8) { issueA(j + 1); issueW(j + 1); }
        computeChunk(cur, acc);
        __syncthreads();
        if (j < 8) {
            writeA(cur ^ 1); writeW(cur ^ 1);
        } else {
            // final chunk: stage head weights + relu'd hT into the free buffers
            stageWv(1);
            char* hB = (char*)aL[1];
            #pragma unroll
            for (int cf = 0; cf < 4; ++cf)
                #pragma unroll
                for (int r = 0; r < 4; ++r) {
                    float hval = fmaxf(acc[cf][r], 0.f);
                    int row = w * 16 + kh * 4 + r;       // C/D: row=(l>>4)*4+r
                    int col = cf * 16 + cq;              //      col=l&15 (+16*cf)
                    *reinterpret_cast<u16*>(hB + swz(row, col * 2)) = f2bf(hval);
                }
        }
        __syncthreads();
    }

    // ---- value head: value = hT @ Wv  (K=64) ----
    f32x4 vacc[4];
    #pragma unroll
    for (int cf = 0; cf < 4; ++cf) vacc[cf] = f32x4{0.f, 0.f, 0.f, 0.f};
    computeChunk(1, vacc);   // aL[1]=hT, wL[1]=Wv — same tile code path

    #pragma unroll
    for (int cf = 0; cf < 4; ++cf)
        #pragma unroll
        for (int r = 0; r < 4; ++r) {
            int node = base + w * 16 + kh * 4 + r;
            if (node < N)
                value_out[(size_t)node * 64 + cf * 16 + cq] = vacc[cf][r];
        }

    // ---- parent: write bf16 h to workspace (coalesced via LDS readback) ----
    if (!IS_CHILD) {
        int node = base + ln;
        if (node < N) {
            const char* hB = (const char*)aL[1];
            short8 x0 = *reinterpret_cast<const short8*>(hB + swz(ln, s * 32));
            short8 x1 = *reinterpret_cast<const short8*>(hB + swz(ln, s * 32 + 16));
            u16* dst = h_out + (size_t)node * 64 + s * 16;
            *reinterpret_cast<short8*>(dst)     = x0;
            *reinterpret_cast<short8*>(dst + 8) = x1;
        }
    }

    // ---- split head: split[n] = dot(h[n], Ws); 4 lanes per node ----
    {
        const char* hB = (const char*)aL[1];
        float sp = 0.f;
        #pragma unroll
        for (int u2 = 0; u2 < 2; ++u2) {
            short8 hv = *reinterpret_cast<const short8*>(hB + swz(ln, s * 32 + u2 * 16));
            #pragma unroll
            for (int e = 0; e < 8; ++e)
                sp += bf2f((u16)hv[e]) * Ws[s * 16 + u2 * 8 + e];
        }
        sp += __shfl_xor(sp, 1);
        sp += __shfl_xor(sp, 2);
        if (s == 0) {
            int node = base + ln;
            if (node < N) split_out[node] = sp;
        }
    }
}

extern "C" void kernel_launch(void* const* d_in, const int* in_sizes, int n_in,
                              void* d_out, int out_size, void* d_ws, size_t ws_size,
                              hipStream_t stream) {
    const float* feat       = (const float*)d_in[0];
    const int*   neigh_d    = (const int*)d_in[1];
    const int*   neigh_d1   = (const int*)d_in[2];
    const int*   parent_idx = (const int*)d_in[3];
    const float* split_gt   = (const float*)d_in[4];
    const float* W1  = (const float*)d_in[5];
    const float* b1  = (const float*)d_in[6];
    const float* W2  = (const float*)d_in[7];
    const float* b2  = (const float*)d_in[8];
    const float* Ws1 = (const float*)d_in[9];
    const float* Wv1 = (const float*)d_in[10];
    const float* Ws2 = (const float*)d_in[11];
    const float* Wv2 = (const float*)d_in[12];

    float* out    = (float*)d_out;
    float* split1 = out;
    float* value1 = out + NPARENT;
    float* split2 = out + NPARENT + (size_t)NPARENT * 64;
    float* value2 = split2 + NCHILD;

    // workspace layout (bf16): h[200000][64], Wt1[64][576], Wt2, Wv1t[64][64], Wv2t
    u16* h_ws = (u16*)d_ws;
    u16* Wt1  = h_ws + (size_t)NPARENT * 64;
    u16* Wt2  = Wt1 + 576 * 64;
    u16* Wv1t = Wt2 + 576 * 64;
    u16* Wv2t = Wv1t + 64 * 64;

    prep_w<<<144, 256, 0, stream>>>(W1, W2, Wv1, Wv2, Wt1, Wt2, Wv1t, Wv2t);

    quad_mfma<false><<<NPARENT / 64, 256, 0, stream>>>(
        feat, nullptr, neigh_d, nullptr, nullptr,
        Wt1, b1, Ws1, Wv1t, split1, value1, h_ws, NPARENT);

    quad_mfma<true><<<(NCHILD + 63) / 64, 256, 0, stream>>>(
        nullptr, h_ws, neigh_d1, parent_idx, split_gt,
        Wt2, b2, Ws2, Wv2t, split2, value2, nullptr, NCHILD);
}

// Round 4
// 158.412 us; speedup vs baseline: 4.9077x; 1.1856x over previous
//
#include <hip/hip_runtime.h>

// TreeDecoderTeacherForced — R3: prefused child gather indices (chain 4->2,
// gate folded into idx), bf16 feat for parent gather (halved bytes),
// ws-size-guarded fallbacks. Core MFMA structure unchanged from R2.

using short8 = __attribute__((ext_vector_type(8))) short;
using us4    = __attribute__((ext_vector_type(4))) unsigned short;
using f32x4  = __attribute__((ext_vector_type(4))) float;
typedef unsigned int u32;
typedef unsigned short u16;

constexpr int NPARENT = 200000;
constexpr int NCHILD  = 300000;

__device__ __forceinline__ u16 f2bf(float x) {        // fp32 -> bf16 RNE
    u32 u = __builtin_bit_cast(u32, x);
    u32 r = (u + 0x7fffu + ((u >> 16) & 1u)) >> 16;
    return (u16)r;
}
__device__ __forceinline__ float bf2f(u16 x) {
    u32 u = ((u32)x) << 16;
    return __builtin_bit_cast(float, u);
}
// swizzled byte offset in a [64 rows][64 bf16] tile (row stride 128 B).
__device__ __forceinline__ int swz(int row, int byteInRow) {
    return row * 128 + (byteInRow ^ ((row & 7) << 4));
}

// ---------------- prep: weights -> bf16 transposed ----------------
__global__ __launch_bounds__(256)
void prep_w(const float* __restrict__ W1, const float* __restrict__ W2,
            const float* __restrict__ Wv1, const float* __restrict__ Wv2,
            u16* __restrict__ Wt1, u16* __restrict__ Wt2,
            u16* __restrict__ Wv1t, u16* __restrict__ Wv2t)
{
    int t = blockIdx.x * 256 + threadIdx.x;
    if (t < 576 * 64) {
        int k = t >> 6, c = t & 63;
        Wt1[c * 576 + k] = f2bf(W1[t]);
        Wt2[c * 576 + k] = f2bf(W2[t]);
    }
    if (t < 64 * 64) {
        int k = t >> 6, c = t & 63;
        Wv1t[c * 64 + k] = f2bf(Wv1[t]);
        Wv2t[c * 64 + k] = f2bf(Wv2[t]);
    }
}

// ---------------- prep: feat fp32 -> bf16 ----------------
__global__ __launch_bounds__(256)
void prep_feat(const float* __restrict__ feat, u16* __restrict__ featb, int n8)
{
    int t = blockIdx.x * 256 + threadIdx.x;
    if (t >= n8) return;
    const float4 a = *reinterpret_cast<const float4*>(feat + (size_t)t * 8);
    const float4 b = *reinterpret_cast<const float4*>(feat + (size_t)t * 8 + 4);
    short8 o;
    o[0]=(short)f2bf(a.x); o[1]=(short)f2bf(a.y); o[2]=(short)f2bf(a.z); o[3]=(short)f2bf(a.w);
    o[4]=(short)f2bf(b.x); o[5]=(short)f2bf(b.y); o[6]=(short)f2bf(b.z); o[7]=(short)f2bf(b.w);
    *reinterpret_cast<short8*>(featb + (size_t)t * 8) = o;
}

// ---------------- prep: fuse child gather indices ----------------
// fused = -1 if neighbor missing OR parent gate == 0, else parent row index.
__global__ __launch_bounds__(256)
void prep_idx(const int* __restrict__ neigh_d1, const int* __restrict__ parent_idx,
              const float* __restrict__ split_gt, int* __restrict__ fused, int n)
{
    int t = blockIdx.x * 256 + threadIdx.x;
    if (t >= n) return;
    int g = neigh_d1[t];
    int e = -1;
    if (g >= 0) {
        int p = parent_idx[g];
        if (split_gt[p] != 0.0f) e = p;
    }
    fused[t] = e;
}

// ---------------- main fused conv + heads kernel ----------------
// MODE: 0 = parent, fp32 feat (fallback)   1 = parent, bf16 feat
//       2 = child, fused idx               3 = child, unfused (fallback)
template<int MODE>
__global__ __launch_bounds__(256)
void quad_mfma(const float*  __restrict__ src_f32,    // MODE 0
               const u16*    __restrict__ src_b16,    // MODE 1: featb; 2/3: h
               const int*    __restrict__ idx,        // 0/1/3: neigh; 2: fused
               const int*    __restrict__ parent_idx, // MODE 3 only
               const float*  __restrict__ split_gt,   // MODE 3 only
               const u16*    __restrict__ Wt,         // [64][576] bf16
               const float*  __restrict__ bvec,
               const float*  __restrict__ Ws,
               const u16*    __restrict__ Wvt,        // [64][64] bf16
               float* __restrict__ split_out,
               float* __restrict__ value_out,
               u16*   __restrict__ h_out,             // parent modes only
               int N)
{
    __shared__ u16 aL[2][64 * 64];
    __shared__ u16 wL[2][64 * 64];

    const int tid  = threadIdx.x;
    const int lane = tid & 63;
    const int w    = tid >> 6;
    const int cq   = lane & 15;
    const int kh   = lane >> 4;
    const int base = blockIdx.x * 64;
    const int ln   = tid >> 2;        // staging: local node / weight row 0..63
    const int s    = tid & 3;         // staging: 16-col sub-slot

    float4 avP[4];
    short8 avB[2];
    short8 wv2[2];

    auto issueA = [&](int j) {
        if (MODE == 0) {
            #pragma unroll
            for (int u = 0; u < 4; ++u) avP[u] = make_float4(0.f,0.f,0.f,0.f);
        } else {
            avB[0] = short8{0,0,0,0,0,0,0,0}; avB[1] = avB[0];
        }
        const int node = base + ln;
        if (node < N) {
            const int g = idx[node * 9 + j];
            if (g >= 0) {
                if (MODE == 0) {
                    const float* src = src_f32 + (size_t)g * 64 + s * 16;
                    #pragma unroll
                    for (int u = 0; u < 4; ++u)
                        avP[u] = *reinterpret_cast<const float4*>(src + u * 4);
                } else if (MODE == 1 || MODE == 2) {
                    const u16* src = src_b16 + (size_t)g * 64 + s * 16;
                    avB[0] = *reinterpret_cast<const short8*>(src);
                    avB[1] = *reinterpret_cast<const short8*>(src + 8);
                } else {   // MODE 3: unfused child
                    const int p = parent_idx[g];
                    if (split_gt[p] != 0.0f) {
                        const u16* src = src_b16 + (size_t)p * 64 + s * 16;
                        avB[0] = *reinterpret_cast<const short8*>(src);
                        avB[1] = *reinterpret_cast<const short8*>(src + 8);
                    }
                }
            }
        }
    };
    auto writeA = [&](int buf) {
        char* aB = (char*)aL[buf];
        if (MODE == 0) {
            #pragma unroll
            for (int u = 0; u < 4; ++u) {
                us4 t4 = { f2bf(avP[u].x), f2bf(avP[u].y),
                           f2bf(avP[u].z), f2bf(avP[u].w) };
                *reinterpret_cast<us4*>(aB + swz(ln, s * 32 + u * 8)) = t4;
            }
        } else {
            #pragma unroll
            for (int u = 0; u < 2; ++u)
                *reinterpret_cast<short8*>(aB + swz(ln, s * 32 + u * 16)) = avB[u];
        }
    };
    auto issueW = [&](int j) {
        const u16* src = Wt + (size_t)ln * 576 + j * 64 + s * 16;
        wv2[0] = *reinterpret_cast<const short8*>(src);
        wv2[1] = *reinterpret_cast<const short8*>(src + 8);
    };
    auto writeW = [&](int buf) {
        char* wB = (char*)wL[buf];
        #pragma unroll
        for (int u = 0; u < 2; ++u)
            *reinterpret_cast<short8*>(wB + swz(ln, s * 32 + u * 16)) = wv2[u];
    };
    auto stageWv = [&](int buf) {
        const u16* src = Wvt + (size_t)ln * 64 + s * 16;
        short8 a = *reinterpret_cast<const short8*>(src);
        short8 b = *reinterpret_cast<const short8*>(src + 8);
        char* wB = (char*)wL[buf];
        *reinterpret_cast<short8*>(wB + swz(ln, s * 32))      = a;
        *reinterpret_cast<short8*>(wB + swz(ln, s * 32 + 16)) = b;
    };

    f32x4 acc[4];
    #pragma unroll
    for (int cf = 0; cf < 4; ++cf) {
        float b = bvec[cf * 16 + cq];
        acc[cf] = f32x4{b, b, b, b};
    }

    auto computeChunk = [&](int buf, f32x4* ac) {
        const char* aB = (const char*)aL[buf];
        const char* wB = (const char*)wL[buf];
        #pragma unroll
        for (int ks = 0; ks < 2; ++ks) {
            const int arow = w * 16 + cq;
            short8 afrag = *reinterpret_cast<const short8*>(aB + swz(arow, ks * 64 + kh * 16));
            #pragma unroll
            for (int cf = 0; cf < 4; ++cf) {
                const int brow = cf * 16 + cq;
                short8 bfrag = *reinterpret_cast<const short8*>(wB + swz(brow, ks * 64 + kh * 16));
                ac[cf] = __builtin_amdgcn_mfma_f32_16x16x32_bf16(afrag, bfrag, ac[cf], 0, 0, 0);
            }
        }
    };

    // prologue
    issueA(0); issueW(0);
    writeA(0); writeW(0);
    __syncthreads();

    for (int j = 0; j < 9; ++j) {
        const int cur = j & 1;
        if (j < 8) { issueA(j + 1); issueW(j + 1); }
        computeChunk(cur, acc);
        __syncthreads();
        if (j < 8) {
            writeA(cur ^ 1); writeW(cur ^ 1);
        } else {
            stageWv(1);
            char* hB = (char*)aL[1];
            #pragma unroll
            for (int cf = 0; cf < 4; ++cf)
                #pragma unroll
                for (int r = 0; r < 4; ++r) {
                    float hval = fmaxf(acc[cf][r], 0.f);
                    int row = w * 16 + kh * 4 + r;
                    int col = cf * 16 + cq;
                    *reinterpret_cast<u16*>(hB + swz(row, col * 2)) = f2bf(hval);
                }
        }
        __syncthreads();
    }

    // value head
    f32x4 vacc[4];
    #pragma unroll
    for (int cf = 0; cf < 4; ++cf) vacc[cf] = f32x4{0.f, 0.f, 0.f, 0.f};
    computeChunk(1, vacc);

    #pragma unroll
    for (int cf = 0; cf < 4; ++cf)
        #pragma unroll
        for (int r = 0; r < 4; ++r) {
            int node = base + w * 16 + kh * 4 + r;
            if (node < N)
                value_out[(size_t)node * 64 + cf * 16 + cq] = vacc[cf][r];
        }

    // parent: write bf16 h (ungated) to workspace
    if (MODE == 0 || MODE == 1) {
        int node = base + ln;
        if (node < N) {
            const char* hB = (const char*)aL[1];
            short8 x0 = *reinterpret_cast<const short8*>(hB + swz(ln, s * 32));
            short8 x1 = *reinterpret_cast<const short8*>(hB + swz(ln, s * 32 + 16));
            u16* dst = h_out + (size_t)node * 64 + s * 16;
            *reinterpret_cast<short8*>(dst)     = x0;
            *reinterpret_cast<short8*>(dst + 8) = x1;
        }
    }

    // split head
    {
        const char* hB = (const char*)aL[1];
        float sp = 0.f;
        #pragma unroll
        for (int u2 = 0; u2 < 2; ++u2) {
            short8 hv = *reinterpret_cast<const short8*>(hB + swz(ln, s * 32 + u2 * 16));
            #pragma unroll
            for (int e = 0; e < 8; ++e)
                sp += bf2f((u16)hv[e]) * Ws[s * 16 + u2 * 8 + e];
        }
        sp += __shfl_xor(sp, 1);
        sp += __shfl_xor(sp, 2);
        if (s == 0) {
            int node = base + ln;
            if (node < N) split_out[node] = sp;
        }
    }
}

extern "C" void kernel_launch(void* const* d_in, const int* in_sizes, int n_in,
                              void* d_out, int out_size, void* d_ws, size_t ws_size,
                              hipStream_t stream) {
    const float* feat       = (const float*)d_in[0];
    const int*   neigh_d    = (const int*)d_in[1];
    const int*   neigh_d1   = (const int*)d_in[2];
    const int*   parent_idx = (const int*)d_in[3];
    const float* split_gt   = (const float*)d_in[4];
    const float* W1  = (const float*)d_in[5];
    const float* b1  = (const float*)d_in[6];
    const float* W2  = (const float*)d_in[7];
    const float* b2  = (const float*)d_in[8];
    const float* Ws1 = (const float*)d_in[9];
    const float* Wv1 = (const float*)d_in[10];
    const float* Ws2 = (const float*)d_in[11];
    const float* Wv2 = (const float*)d_in[12];

    float* out    = (float*)d_out;
    float* split1 = out;
    float* value1 = out + NPARENT;
    float* split2 = out + NPARENT + (size_t)NPARENT * 64;
    float* value2 = split2 + NCHILD;

    // ---- workspace layout (u16 units unless noted) ----
    u16* h_ws = (u16*)d_ws;                          // [200000][64] bf16, ungated
    u16* Wt1  = h_ws + (size_t)NPARENT * 64;
    u16* Wt2  = Wt1 + 576 * 64;
    u16* Wv1t = Wt2 + 576 * 64;
    u16* Wv2t = Wv1t + 64 * 64;
    u16* endW = Wv2t + 64 * 64;
    size_t offW_bytes = (size_t)(endW - (u16*)d_ws) * 2;

    int*  fused = (int*)((char*)d_ws + offW_bytes);  // [300000][9] int32
    size_t offF_bytes = offW_bytes + (size_t)NCHILD * 9 * 4;
    u16*  featb = (u16*)((char*)d_ws + offF_bytes);  // [200000][64] bf16
    size_t offB_bytes = offF_bytes + (size_t)NPARENT * 64 * 2;

    const bool useFused = ws_size >= offF_bytes;
    const bool useFeatb = ws_size >= offB_bytes;

    prep_w<<<144, 256, 0, stream>>>(W1, W2, Wv1, Wv2, Wt1, Wt2, Wv1t, Wv2t);
    if (useFeatb)
        prep_feat<<<(NPARENT * 64 / 8 + 255) / 256, 256, 0, stream>>>(
            feat, featb, NPARENT * 64 / 8);
    if (useFused)
        prep_idx<<<(NCHILD * 9 + 255) / 256, 256, 0, stream>>>(
            neigh_d1, parent_idx, split_gt, fused, NCHILD * 9);

    if (useFeatb)
        quad_mfma<1><<<NPARENT / 64, 256, 0, stream>>>(
            nullptr, featb, neigh_d, nullptr, nullptr,
            Wt1, b1, Ws1, Wv1t, split1, value1, h_ws, NPARENT);
    else
        quad_mfma<0><<<NPARENT / 64, 256, 0, stream>>>(
            feat, nullptr, neigh_d, nullptr, nullptr,
            Wt1, b1, Ws1, Wv1t, split1, value1, h_ws, NPARENT);

    if (useFused)
        quad_mfma<2><<<(NCHILD + 63) / 64, 256, 0, stream>>>(
            nullptr, h_ws, fused, nullptr, nullptr,
            Wt2, b2, Ws2, Wv2t, split2, value2, nullptr, NCHILD);
    else
        quad_mfma<3><<<(NCHILD + 63) / 64, 256, 0, stream>>>(
            nullptr, h_ws, neigh_d1, parent_idx, split_gt,
            Wt2, b2, Ws2, Wv2t, split2, value2, nullptr, NCHILD);
}